// Round 7
// baseline (1021.081 us; speedup 1.0000x reference)
//
#include <hip/hip_runtime.h>

#define NN    8192
#define NL    16
#define NE    (NN * 128)
#define NOUTC 16
#define EOUTC (NN * NOUTC)

#define NBLK  256
#define NTHR  1024
#define EPB   (NE / NBLK)    // 4096 edges per block per layer

#define AGENT __HIP_MEMORY_SCOPE_AGENT

__device__ __forceinline__ float lrelu(float v) { return v >= 0.f ? v : 0.01f * v; }

// relaxed agent-scope ops: route via the coherent LLC, bypass per-XCD L2 staleness
__device__ __forceinline__ float gload(const float* p) {
    return __hip_atomic_load(p, __ATOMIC_RELAXED, AGENT);
}
__device__ __forceinline__ void gstore(float* p, float v) {
    __hip_atomic_store(p, v, __ATOMIC_RELAXED, AGENT);
}

// ---- lightweight device-wide barrier ----
// bar layout (ints): [0..255] 16 sub-counters at stride 16 (own cache line each),
//                    [256]    master counter (own line),
//                    [272]    generation flag (own line)
// Monotonic counters; caller passes epoch = 1,2,3,...
// Called by thread 0 of each block, AFTER __syncthreads() (which drains the
// block's outstanding stores via the compiler's s_waitcnt before s_barrier).
__device__ __forceinline__ void gbarrier(int* bar, int b, int epoch) {
    int old = __hip_atomic_fetch_add(&bar[(b & 15) * 16], 1, __ATOMIC_ACQ_REL, AGENT);
    if (old == epoch * 16 - 1) {                 // last arriver in this sub-group
        int mo = __hip_atomic_fetch_add(&bar[256], 1, __ATOMIC_ACQ_REL, AGENT);
        if (mo == epoch * 16 - 1) {              // last sub-group overall
            __hip_atomic_store(&bar[272], epoch, __ATOMIC_RELEASE, AGENT);
        }
    }
    while (__hip_atomic_load(&bar[272], __ATOMIC_ACQUIRE, AGENT) < epoch) {
        __builtin_amdgcn_s_sleep(1);
    }
}

// NOTE: must launch with >= 288 threads (R6 bug: 256-thread launch left the
// master counter + generation flag poisoned 0xAA -> permanent spin -> GPU hang)
__global__ __launch_bounds__(512) void zero_bar_kernel(int* __restrict__ bar) {
    if (threadIdx.x < 288) bar[threadIdx.x] = 0;
}

__global__ __launch_bounds__(NTHR) void nn_kernel(
    const float* __restrict__ x,
    const float* __restrict__ edge_w,
    const int*   __restrict__ edge_src,
    const int*   __restrict__ edge_dst,
    const float* __restrict__ out_w,
    const int*   __restrict__ out_src,
    const int*   __restrict__ out_dst,
    float* __restrict__ partials,   // [NBLK][NN]
    float* __restrict__ accv,       // [NN] activated layer vector
    float* __restrict__ outs,       // [NBLK][NOUTC]
    int*   __restrict__ bar,        // 288 ints, pre-zeroed
    float* __restrict__ out)        // d_out
{
    __shared__ float vals[NN];      // activated source values (aliased as sred in reduce)
    __shared__ float accs[NN];      // block-private accumulator
    __shared__ float bins[NOUTC];

    const int tid = threadIdx.x;
    const int b   = blockIdx.x;
    int ep = 0;

    for (int l = 0; l < NL; ++l) {
        // ---- stage activated source vector into LDS; zero private acc ----
        if (l == 0) {
            for (int i = tid * 4; i < NN; i += NTHR * 4)
                *(float4*)(vals + i) = *(const float4*)(x + i);
        } else {
            for (int i = tid; i < NN; i += NTHR)
                vals[i] = gload(accv + i);       // LLC hit, post-barrier fresh
        }
        for (int i = tid * 4; i < NN; i += NTHR * 4)
            *(float4*)(accs + i) = make_float4(0.f, 0.f, 0.f, 0.f);
        __syncthreads();

        // ---- scatter: one edge quad per thread (NTHR*4 == EPB) ----
        {
            const size_t eb = (size_t)l * NE + (size_t)b * EPB + (size_t)tid * 4;
            int4   s = *(const int4*)(edge_src + eb);
            int4   d = *(const int4*)(edge_dst + eb);
            float4 w = *(const float4*)(edge_w + eb);
            atomicAdd(&accs[d.x], vals[s.x] * w.x);
            atomicAdd(&accs[d.y], vals[s.y] * w.y);
            atomicAdd(&accs[d.z], vals[s.z] * w.z);
            atomicAdd(&accs[d.w], vals[s.w] * w.w);
        }
        __syncthreads();

        // ---- flush private partial to LLC (8 scalar agent stores/thread) ----
        for (int i = tid; i < NN; i += NTHR)
            gstore(partials + (size_t)b * NN + i, accs[i]);
        __syncthreads();                          // drains stores (vmcnt) per wave
        ++ep; if (tid == 0) gbarrier(bar, b, ep);
        __syncthreads();

        // ---- reduce: block owns 32 neurons; 8-row k-split per thread ----
        {
            const int kg = tid >> 5;              // 0..31
            const int nl = tid & 31;
            const int n  = b * 32 + nl;
            float s = 0.f;
            #pragma unroll
            for (int j = 0; j < 8; ++j)
                s += gload(partials + (size_t)(kg + 32 * j) * NN + n);
            float* sred = vals;                   // alias: vals free until next stage
            sred[kg * 33 + nl] = s;
            __syncthreads();
            if (tid < 32) {
                float t = 0.f;
                #pragma unroll
                for (int r = 0; r < 32; ++r) t += sred[r * 33 + tid];
                gstore(accv + b * 32 + tid, lrelu(t));
            }
        }
        __syncthreads();                          // drains accv stores
        ++ep; if (tid == 0) gbarrier(bar, b, ep);
        __syncthreads();
    }

    // ---- output layer: 512 edges per block into 16 LDS bins ----
    if (tid < NOUTC) bins[tid] = 0.f;
    __syncthreads();
    if (tid < 512) {
        const int g = b * 512 + tid;              // EOUTC == NBLK*512 exactly
        atomicAdd(&bins[out_dst[g]], gload(accv + out_src[g]) * out_w[g]);
    }
    __syncthreads();
    if (tid < NOUTC) gstore(outs + (size_t)b * NOUTC + tid, bins[tid]);
    __syncthreads();
    ++ep; if (tid == 0) gbarrier(bar, b, ep);
    __syncthreads();

    // ---- final: block 0 reduces 256x16, lrelu, softmax ----
    if (b == 0) {
        float* red = vals;
        if (tid < 256) {
            const int j = tid & 15, g = tid >> 4;
            float s = 0.f;
            #pragma unroll
            for (int r = 0; r < 16; ++r)
                s += gload(outs + (size_t)(g + r * 16) * NOUTC + j);
            red[g * 17 + j] = s;
        }
        __syncthreads();
        if (tid < NOUTC) {
            float t = 0.f;
            #pragma unroll
            for (int g2 = 0; g2 < 16; ++g2) t += red[g2 * 17 + tid];
            float v = lrelu(t);
            float m = v;
            #pragma unroll
            for (int off = 8; off >= 1; off >>= 1)
                m = fmaxf(m, __shfl_xor(m, off, 64));
            float e = __expf(v - m);
            float ssum = e;
            #pragma unroll
            for (int off = 8; off >= 1; off >>= 1)
                ssum += __shfl_xor(ssum, off, 64);
            out[tid] = e / ssum;
        }
    }
}

extern "C" void kernel_launch(void* const* d_in, const int* in_sizes, int n_in,
                              void* d_out, int out_size, void* d_ws, size_t ws_size,
                              hipStream_t stream) {
    const float* x        = (const float*)d_in[0];
    const float* edge_w   = (const float*)d_in[1];
    const float* out_w    = (const float*)d_in[2];
    const int*   edge_src = (const int*)d_in[3];
    const int*   edge_dst = (const int*)d_in[4];
    const int*   out_src  = (const int*)d_in[5];
    const int*   out_dst  = (const int*)d_in[6];

    float* partials = (float*)d_ws;                     // 8 MB
    float* accv     = partials + (size_t)NBLK * NN;     // 32 KB
    float* outs     = accv + NN;                        // 16 KB
    int*   bar      = (int*)(outs + NBLK * NOUTC);      // 288 ints
    float* out      = (float*)d_out;

    zero_bar_kernel<<<1, 512, 0, stream>>>(bar);

    void* args[] = { (void*)&x, (void*)&edge_w, (void*)&edge_src, (void*)&edge_dst,
                     (void*)&out_w, (void*)&out_src, (void*)&out_dst,
                     (void*)&partials, (void*)&accv, (void*)&outs, (void*)&bar,
                     (void*)&out };

    hipLaunchCooperativeKernel((const void*)nn_kernel,
                               dim3(NBLK), dim3(NTHR),
                               args, 0, stream);
}

// Round 8
// 901.194 us; speedup vs baseline: 1.1330x; 1.1330x over previous
//
#include <hip/hip_runtime.h>

#define NN    8192
#define NL    16
#define NE    (NN * 128)
#define NOUTC 16
#define EOUTC (NN * NOUTC)

#define NBLK  256
#define NTHR  1024
#define EPB   (NE / NBLK)    // 4096 edges per block per layer
#define NH    (NN / 2)       // 4096 float2 per vector

#define AGENT __HIP_MEMORY_SCOPE_AGENT

typedef unsigned long long u64;

__device__ __forceinline__ float lrelu(float v) { return v >= 0.f ? v : 0.01f * v; }

// 64-bit relaxed agent-scope ops: coherent via LLC, 2x fewer ops than scalar
__device__ __forceinline__ float2 gload2(const u64* p) {
    union { u64 u; float2 f; } c;
    c.u = __hip_atomic_load(p, __ATOMIC_RELAXED, AGENT);
    return c.f;
}
__device__ __forceinline__ void gstore2(u64* p, float2 v) {
    union { u64 u; float2 f; } c;
    c.f = v;
    __hip_atomic_store(p, c.u, __ATOMIC_RELAXED, AGENT);
}
__device__ __forceinline__ float gload1(const float* p) {
    return __hip_atomic_load(p, __ATOMIC_RELAXED, AGENT);
}
__device__ __forceinline__ void gstore1(float* p, float v) {
    __hip_atomic_store(p, v, __ATOMIC_RELAXED, AGENT);
}

// ---- lightweight device-wide barrier ----
// bar: [0..255] 16 sub-counters (stride 16 ints = own line), [256] master, [272] gen flag
// s_sleep(16) poll (~0.4us period) to avoid the same-line LLC polling storm (R7 lesson)
__device__ __forceinline__ void gbarrier(int* bar, int b, int epoch) {
    int old = __hip_atomic_fetch_add(&bar[(b & 15) * 16], 1, __ATOMIC_ACQ_REL, AGENT);
    if (old == epoch * 16 - 1) {                 // last arriver in this sub-group
        int mo = __hip_atomic_fetch_add(&bar[256], 1, __ATOMIC_ACQ_REL, AGENT);
        if (mo == epoch * 16 - 1)                // last sub-group overall
            __hip_atomic_store(&bar[272], epoch, __ATOMIC_RELEASE, AGENT);
    }
    while (__hip_atomic_load(&bar[272], __ATOMIC_ACQUIRE, AGENT) < epoch)
        __builtin_amdgcn_s_sleep(16);
}

// must launch with >= 288 threads (R6 bug)
__global__ __launch_bounds__(512) void zero_bar_kernel(int* __restrict__ bar) {
    if (threadIdx.x < 288) bar[threadIdx.x] = 0;
}

__global__ __launch_bounds__(NTHR) void nn_kernel(
    const float* __restrict__ x,
    const float* __restrict__ edge_w,
    const int*   __restrict__ edge_src,
    const int*   __restrict__ edge_dst,
    const float* __restrict__ out_w,
    const int*   __restrict__ out_src,
    const int*   __restrict__ out_dst,
    u64*   __restrict__ partials2,  // [NBLK][NH] float2
    u64*   __restrict__ accv2,      // [NH] float2, activated layer vector
    float* __restrict__ outs,       // [NBLK][NOUTC]
    int*   __restrict__ bar,        // 288 ints, pre-zeroed
    float* __restrict__ out)        // d_out
{
    __shared__ float vals[NN];      // activated source values (aliased by reduce stage 1)
    __shared__ float accs[NN];      // block-private accumulator (aliased by reduce stage 2)
    __shared__ float bins[NOUTC];

    const int tid = threadIdx.x;
    const int b   = blockIdx.x;
    int ep = 0;

    for (int l = 0; l < NL; ++l) {
        // ---- stage activated source vector into LDS; zero private acc ----
        if (l == 0) {
            for (int i = tid * 4; i < NN; i += NTHR * 4)
                *(float4*)(vals + i) = *(const float4*)(x + i);
        } else {
            for (int i = tid; i < NH; i += NTHR)          // 4 x b64 coherent loads
                *(float2*)(vals + 2 * i) = gload2(accv2 + i);
        }
        for (int i = tid * 4; i < NN; i += NTHR * 4)
            *(float4*)(accs + i) = make_float4(0.f, 0.f, 0.f, 0.f);
        __syncthreads();

        // ---- scatter: one edge quad per thread (NTHR*4 == EPB) ----
        {
            const size_t eb = (size_t)l * NE + (size_t)b * EPB + (size_t)tid * 4;
            int4   s = *(const int4*)(edge_src + eb);
            int4   d = *(const int4*)(edge_dst + eb);
            float4 w = *(const float4*)(edge_w + eb);
            atomicAdd(&accs[d.x], vals[s.x] * w.x);
            atomicAdd(&accs[d.y], vals[s.y] * w.y);
            atomicAdd(&accs[d.z], vals[s.z] * w.z);
            atomicAdd(&accs[d.w], vals[s.w] * w.w);
        }
        __syncthreads();

        // ---- flush private partial to LLC (4 x b64 stores/thread) ----
        {
            u64* prow = partials2 + (size_t)b * NH;
            for (int i = tid; i < NH; i += NTHR)
                gstore2(prow + i, *(const float2*)(accs + 2 * i));
        }
        __syncthreads();                          // drains stores (vmcnt) per wave
        ++ep; if (tid == 0) gbarrier(bar, b, ep);
        __syncthreads();

        // ---- reduce: block owns 32 neurons (16 float2 cols); 256 rows k-split ----
        {
            const int col = tid & 15;             // float2 column 0..15
            const int rg  = tid >> 4;             // row group 0..63
            const u64* p0 = partials2 + (size_t)rg * NH + b * 16 + col;
            float2 s = make_float2(0.f, 0.f);
            #pragma unroll
            for (int j = 0; j < 4; ++j) {         // rows rg + 64*j
                float2 v = gload2(p0 + (size_t)(64 * j) * NH);
                s.x += v.x; s.y += v.y;
            }
            float2* sred = (float2*)vals;         // alias: vals free after scatter
            sred[rg * 16 + col] = s;              // lane-linear b64 -> conflict-free
            __syncthreads();
            float2* sred2 = (float2*)accs;        // alias: accs free after flush
            if (tid < 256) {
                const int c2 = tid & 15, r2 = tid >> 4;   // 16 groups of 4 rows
                float2 t = make_float2(0.f, 0.f);
                #pragma unroll
                for (int k = 0; k < 4; ++k) {
                    float2 v = sred[(r2 * 4 + k) * 16 + c2];
                    t.x += v.x; t.y += v.y;
                }
                sred2[r2 * 16 + c2] = t;
            }
            __syncthreads();
            if (tid < 16) {
                float2 t = make_float2(0.f, 0.f);
                #pragma unroll
                for (int r = 0; r < 16; ++r) {
                    float2 v = sred2[r * 16 + tid];
                    t.x += v.x; t.y += v.y;
                }
                t.x = lrelu(t.x); t.y = lrelu(t.y);
                gstore2(accv2 + b * 16 + tid, t); // activated
            }
        }
        __syncthreads();                          // drains accv stores
        ++ep; if (tid == 0) gbarrier(bar, b, ep);
        __syncthreads();
    }

    // ---- output layer: 512 edges per block into 16 LDS bins ----
    if (tid < NOUTC) bins[tid] = 0.f;
    __syncthreads();
    if (tid < 512) {
        const int g = b * 512 + tid;              // EOUTC == NBLK*512 exactly
        atomicAdd(&bins[out_dst[g]], gload1((const float*)accv2 + out_src[g]) * out_w[g]);
    }
    __syncthreads();
    if (tid < NOUTC) gstore1(outs + (size_t)b * NOUTC + tid, bins[tid]);
    __syncthreads();
    ++ep; if (tid == 0) gbarrier(bar, b, ep);
    __syncthreads();

    // ---- final: block 0 reduces 256x16, lrelu, softmax ----
    if (b == 0) {
        float* red = vals;
        if (tid < 256) {
            const int j = tid & 15, g = tid >> 4;
            float s = 0.f;
            #pragma unroll
            for (int r = 0; r < 16; ++r)
                s += gload1(outs + (size_t)(g + r * 16) * NOUTC + j);
            red[g * 17 + j] = s;
        }
        __syncthreads();
        if (tid < NOUTC) {
            float t = 0.f;
            #pragma unroll
            for (int g2 = 0; g2 < 16; ++g2) t += red[g2 * 17 + tid];
            float v = lrelu(t);
            float m = v;
            #pragma unroll
            for (int off = 8; off >= 1; off >>= 1)
                m = fmaxf(m, __shfl_xor(m, off, 64));
            float e = __expf(v - m);
            float ssum = e;
            #pragma unroll
            for (int off = 8; off >= 1; off >>= 1)
                ssum += __shfl_xor(ssum, off, 64);
            out[tid] = e / ssum;
        }
    }
}

extern "C" void kernel_launch(void* const* d_in, const int* in_sizes, int n_in,
                              void* d_out, int out_size, void* d_ws, size_t ws_size,
                              hipStream_t stream) {
    const float* x        = (const float*)d_in[0];
    const float* edge_w   = (const float*)d_in[1];
    const float* out_w    = (const float*)d_in[2];
    const int*   edge_src = (const int*)d_in[3];
    const int*   edge_dst = (const int*)d_in[4];
    const int*   out_src  = (const int*)d_in[5];
    const int*   out_dst  = (const int*)d_in[6];

    u64*   partials2 = (u64*)d_ws;                          // 8 MB
    u64*   accv2     = partials2 + (size_t)NBLK * NH;       // 32 KB
    float* outs      = (float*)(accv2 + NH);                // 16 KB
    int*   bar       = (int*)(outs + NBLK * NOUTC);         // 288 ints
    float* out       = (float*)d_out;

    zero_bar_kernel<<<1, 512, 0, stream>>>(bar);

    void* args[] = { (void*)&x, (void*)&edge_w, (void*)&edge_src, (void*)&edge_dst,
                     (void*)&out_w, (void*)&out_src, (void*)&out_dst,
                     (void*)&partials2, (void*)&accv2, (void*)&outs, (void*)&bar,
                     (void*)&out };

    hipLaunchCooperativeKernel((const void*)nn_kernel,
                               dim3(NBLK), dim3(NTHR),
                               args, 0, stream);
}

// Round 9
// 690.464 us; speedup vs baseline: 1.4788x; 1.3052x over previous
//
#include <hip/hip_runtime.h>

#define NN    8192
#define NL    16
#define NE    (NN * 128)
#define NOUTC 16
#define EOUTC (NN * NOUTC)

#define NBLK  256
#define NTHR  1024
#define EPB   (NE / NBLK)    // 4096 edges per block per layer

#define AGENT __HIP_MEMORY_SCOPE_AGENT

__device__ __forceinline__ float lrelu(float v) { return v >= 0.f ? v : 0.01f * v; }

__global__ __launch_bounds__(64) void init_kernel(int* __restrict__ ctr) {
    if (threadIdx.x == 0) *ctr = 0;
}

// One kernel per layer: scatter into private LDS acc -> flush plain float4 ->
// arrive/wait on a monotonic counter (release wbl2 / acquire inv fences) ->
// every block reduces its 32 neurons from all 256 partial rows (plain float4).
__global__ __launch_bounds__(NTHR) void layer_kernel(
    const float* __restrict__ sv,       // source vector (x or accv)
    const int    apply_act,             // 0 for layer 0
    const int*   __restrict__ es,       // this layer's edge_src
    const int*   __restrict__ ed,
    const float* __restrict__ ew,
    float*       __restrict__ partials, // [NBLK][NN]
    float*       __restrict__ accv,     // [NN] activated result
    int*         __restrict__ ctr,      // monotonic arrive counter
    const int    target)                // 256*(l+1)
{
    __shared__ float vals[NN];          // staged source (aliased in reduce stage 2)
    __shared__ float accs[NN];          // private accumulator (aliased as sred)
    const int tid = threadIdx.x;
    const int b   = blockIdx.x;

    // ---- stage source + zero private acc ----
    for (int i = tid * 4; i < NN; i += NTHR * 4) {
        float4 v = *(const float4*)(sv + i);
        if (apply_act) {
            v.x = lrelu(v.x); v.y = lrelu(v.y);
            v.z = lrelu(v.z); v.w = lrelu(v.w);
        }
        *(float4*)(vals + i) = v;
        *(float4*)(accs + i) = make_float4(0.f, 0.f, 0.f, 0.f);
    }
    __syncthreads();

    // ---- scatter: one edge quad per thread (NTHR*4 == EPB) ----
    {
        const size_t e = (size_t)b * EPB + (size_t)tid * 4;
        int4   s = *(const int4*)(es + e);
        int4   d = *(const int4*)(ed + e);
        float4 w = *(const float4*)(ew + e);
        atomicAdd(&accs[d.x], vals[s.x] * w.x);
        atomicAdd(&accs[d.y], vals[s.y] * w.y);
        atomicAdd(&accs[d.z], vals[s.z] * w.z);
        atomicAdd(&accs[d.w], vals[s.w] * w.w);
    }
    __syncthreads();

    // ---- flush private partial: plain cached float4 stores ----
    {
        float* prow = partials + (size_t)b * NN;
        for (int i = tid * 4; i < NN; i += NTHR * 4)
            *(float4*)(prow + i) = *(const float4*)(accs + i);
    }
    __syncthreads();   // compiler emits s_waitcnt vmcnt(0) before s_barrier: stores drained to L2

    // ---- arrive + wait (thread 0 only; fences do L2 writeback / invalidate) ----
    if (tid == 0) {
        __builtin_amdgcn_fence(__ATOMIC_RELEASE, "agent");   // wbl2: flush L2 -> LLC
        __hip_atomic_fetch_add(ctr, 1, __ATOMIC_RELAXED, AGENT);
        while (__hip_atomic_load(ctr, __ATOMIC_RELAXED, AGENT) < target)
            __builtin_amdgcn_s_sleep(8);
        __builtin_amdgcn_fence(__ATOMIC_ACQUIRE, "agent");   // inv L1/L2: see remote partials
    }
    __syncthreads();

    // ---- reduce: block owns neurons [b*32, b*32+32) over 256 rows ----
    {
        float4* sred = (float4*)accs;                 // accs content already flushed
        const int c  = tid & 7;                       // float4 col 0..7 (32 neurons)
        const int rg = tid >> 3;                      // row group 0..127
        const float* p0 = partials + (size_t)rg * NN + b * 32 + c * 4;
        float4 a  = *(const float4*)p0;
        float4 a2 = *(const float4*)(p0 + (size_t)128 * NN);
        a.x += a2.x; a.y += a2.y; a.z += a2.z; a.w += a2.w;
        sred[rg * 8 + c] = a;
        __syncthreads();
        float4* sred2 = (float4*)vals;                // vals no longer needed
        if (tid < 64) {
            const int c2 = tid & 7, r8 = tid >> 3;    // 8 groups of 16 row-groups
            float4 t = make_float4(0.f, 0.f, 0.f, 0.f);
            #pragma unroll
            for (int k = 0; k < 16; ++k) {
                float4 v = sred[(r8 * 16 + k) * 8 + c2];
                t.x += v.x; t.y += v.y; t.z += v.z; t.w += v.w;
            }
            sred2[r8 * 8 + c2] = t;
        }
        __syncthreads();
        if (tid < 8) {
            float4 t = make_float4(0.f, 0.f, 0.f, 0.f);
            #pragma unroll
            for (int r = 0; r < 8; ++r) {
                float4 v = sred2[r * 8 + tid];
                t.x += v.x; t.y += v.y; t.z += v.z; t.w += v.w;
            }
            t.x = lrelu(t.x); t.y = lrelu(t.y);
            t.z = lrelu(t.z); t.w = lrelu(t.w);
            *(float4*)(accv + b * 32 + tid * 4) = t;  // plain store; kernel-end release
        }
    }
}

// ---- output scatter: one edge per thread, 16 LDS bins -> outs[b][16] ----
__global__ __launch_bounds__(512) void out_scatter_kernel(
    const float* __restrict__ accv,
    const int*   __restrict__ out_src,
    const int*   __restrict__ out_dst,
    const float* __restrict__ out_w,
    float*       __restrict__ outs)      // [256][NOUTC]
{
    __shared__ float bins[NOUTC];
    const int tid = threadIdx.x;
    if (tid < NOUTC) bins[tid] = 0.f;
    __syncthreads();
    const int g = blockIdx.x * 512 + tid;           // EOUTC == 256*512 exactly
    atomicAdd(&bins[out_dst[g]], accv[out_src[g]] * out_w[g]);
    __syncthreads();
    if (tid < NOUTC) outs[(size_t)blockIdx.x * NOUTC + tid] = bins[tid];
}

// ---- final: reduce 256x16, lrelu, softmax ----
__global__ __launch_bounds__(256) void final_kernel(
    const float* __restrict__ outs, float* __restrict__ out)
{
    __shared__ float red[16][17];
    const int tid = threadIdx.x;
    const int j = tid & 15, g = tid >> 4;            // 16 groups x 16 bins
    float s = 0.f;
    #pragma unroll
    for (int r = 0; r < 256 / 16; ++r)
        s += outs[(size_t)(g + r * 16) * NOUTC + j];
    red[g][j] = s;
    __syncthreads();
    if (tid < NOUTC) {
        float t = 0.f;
        #pragma unroll
        for (int g2 = 0; g2 < 16; ++g2) t += red[g2][tid];
        float v = lrelu(t);
        float m = v;
        #pragma unroll
        for (int off = 8; off >= 1; off >>= 1)
            m = fmaxf(m, __shfl_xor(m, off, 64));
        float e = __expf(v - m);
        float ssum = e;
        #pragma unroll
        for (int off = 8; off >= 1; off >>= 1)
            ssum += __shfl_xor(ssum, off, 64);
        out[tid] = e / ssum;
    }
}

extern "C" void kernel_launch(void* const* d_in, const int* in_sizes, int n_in,
                              void* d_out, int out_size, void* d_ws, size_t ws_size,
                              hipStream_t stream) {
    const float* x        = (const float*)d_in[0];
    const float* edge_w   = (const float*)d_in[1];
    const float* out_w    = (const float*)d_in[2];
    const int*   edge_src = (const int*)d_in[3];
    const int*   edge_dst = (const int*)d_in[4];
    const int*   out_src  = (const int*)d_in[5];
    const int*   out_dst  = (const int*)d_in[6];

    float* partials = (float*)d_ws;                     // 8 MB
    float* accv     = partials + (size_t)NBLK * NN;     // 32 KB
    float* outs     = accv + NN;                        // 16 KB
    int*   ctr      = (int*)(outs + NBLK * NOUTC);      // 1 int
    float* out      = (float*)d_out;

    init_kernel<<<1, 64, 0, stream>>>(ctr);

    for (int l = 0; l < NL; ++l) {
        const float* sv = (l == 0) ? x : accv;
        layer_kernel<<<NBLK, NTHR, 0, stream>>>(
            sv, l > 0,
            edge_src + (size_t)l * NE,
            edge_dst + (size_t)l * NE,
            edge_w   + (size_t)l * NE,
            partials, accv, ctr, NBLK * (l + 1));
    }

    out_scatter_kernel<<<256, 512, 0, stream>>>(accv, out_src, out_dst, out_w, outs);
    final_kernel<<<1, 256, 0, stream>>>(outs, out);
}

// Round 10
// 439.949 us; speedup vs baseline: 2.3209x; 1.5694x over previous
//
#include <hip/hip_runtime.h>

#define NN    8192
#define NL    16
#define NE    (NN * 128)
#define NOUTC 16
#define EOUTC (NN * NOUTC)

#define NBLK  256
#define NTHR  512
#define EPB   (NE / NBLK)     // 4096 edges per block per layer

__device__ __forceinline__ float lrelu(float v) { return v >= 0.f ? v : 0.01f * v; }

// ---- scatter: gather(LDS) -> LDS private acc -> coalesced dense partial write ----
__global__ __launch_bounds__(NTHR) void scatter_kernel(
    const float* __restrict__ sv,       // activated source vector (x or accv)
    const int*   __restrict__ es,
    const int*   __restrict__ ed,
    const float* __restrict__ ew,
    float*       __restrict__ partials) // [NBLK][NN]
{
    __shared__ float vals[NN];
    __shared__ float accs[NN];
    const int tid = threadIdx.x;
    const int b   = blockIdx.x;

    for (int i = tid * 4; i < NN; i += NTHR * 4) {
        *(float4*)(vals + i) = *(const float4*)(sv + i);
        *(float4*)(accs + i) = make_float4(0.f, 0.f, 0.f, 0.f);
    }
    __syncthreads();

    const int base = b * EPB;
    #pragma unroll
    for (int it = 0; it < EPB / (NTHR * 4); ++it) {   // 2 iterations
        const int e = base + it * NTHR * 4 + tid * 4;
        int4   s = *(const int4*)(es + e);
        int4   d = *(const int4*)(ed + e);
        float4 w = *(const float4*)(ew + e);
        atomicAdd(&accs[d.x], vals[s.x] * w.x);
        atomicAdd(&accs[d.y], vals[s.y] * w.y);
        atomicAdd(&accs[d.z], vals[s.z] * w.z);
        atomicAdd(&accs[d.w], vals[s.w] * w.w);
    }
    __syncthreads();

    float* prow = partials + (size_t)b * NN;
    for (int i = tid * 4; i < NN; i += NTHR * 4)
        *(float4*)(prow + i) = *(const float4*)(accs + i);
}

// ---- reduce 256 partials -> activated layer vector; plus L2 prefetch of the ----
// ---- NEXT phase's edge slice for the same blockIdx (same XCD, round-robin) ----
__global__ __launch_bounds__(256) void reduce_kernel(
    const float* __restrict__ partials,  // [NBLK][NN]
    float*       __restrict__ accv,      // [NN], activated
    const int*   __restrict__ pf_s,      // next phase edge_src
    const int*   __restrict__ pf_d,      // next phase edge_dst
    const float* __restrict__ pf_w,      // next phase edge_w
    const int    pf_half,                // edges per slice (4096 hidden, 512 out)
    float*       __restrict__ sink)      // never-written DCE guard
{
    __shared__ float sred[8][32];
    const int b   = blockIdx.x;          // 256 blocks, 32 neurons each
    const int tid = threadIdx.x;

    // prefetch: issue the next slice's loads first; results only feed a
    // provably-false store, so they overlap the partial reduction below.
    float fs = 0.f;
    {
        const int base = b * pf_half;
        for (int e = tid * 4; e < pf_half; e += 256 * 4) {
            int4   a = *(const int4*)(pf_s + base + e);
            int4   c = *(const int4*)(pf_d + base + e);
            float4 w = *(const float4*)(pf_w + base + e);
            fs += (float)(a.x ^ c.w) + w.x + w.w;   // bounded: idx<8192, |w| small
        }
    }

    const int nl = tid & 31;
    const int kg = tid >> 5;             // 0..7
    const int n  = b * 32 + nl;
    float s = 0.f;
    #pragma unroll
    for (int k = 0; k < NBLK / 8; ++k)
        s += partials[(size_t)(kg + k * 8) * NN + n];
    sred[kg][nl] = s;
    __syncthreads();
    if (tid < 32) {
        float t = 0.f;
        #pragma unroll
        for (int j = 0; j < 8; ++j) t += sred[j][tid];
        accv[b * 32 + tid] = lrelu(t);
    }
    if (fs > 1.0e30f) sink[0] = fs;      // unreachable for these inputs
}

// ---- output scatter: one edge per thread, 16 LDS bins -> outs[b][16] ----
__global__ __launch_bounds__(512) void out_scatter_kernel(
    const float* __restrict__ accv,      // activated layer-15 vector
    const int*   __restrict__ out_src,
    const int*   __restrict__ out_dst,
    const float* __restrict__ out_w,
    float*       __restrict__ outs)      // [256][NOUTC]
{
    __shared__ float bins[NOUTC];
    const int tid = threadIdx.x;
    if (tid < NOUTC) bins[tid] = 0.f;
    __syncthreads();
    const int g = blockIdx.x * 512 + tid;           // EOUTC == 256*512 exactly
    atomicAdd(&bins[out_dst[g]], accv[out_src[g]] * out_w[g]);
    __syncthreads();
    if (tid < NOUTC) outs[(size_t)blockIdx.x * NOUTC + tid] = bins[tid];
}

// ---- final: reduce 256x16, lrelu, softmax ----
__global__ __launch_bounds__(256) void final_kernel(
    const float* __restrict__ outs, float* __restrict__ out)
{
    __shared__ float red[16][17];
    const int tid = threadIdx.x;
    const int j = tid & 15, g = tid >> 4;            // 16 groups x 16 bins
    float s = 0.f;
    #pragma unroll
    for (int r = 0; r < 256 / 16; ++r)
        s += outs[(size_t)(g + r * 16) * NOUTC + j];
    red[g][j] = s;
    __syncthreads();
    if (tid < NOUTC) {
        float t = 0.f;
        #pragma unroll
        for (int g2 = 0; g2 < 16; ++g2) t += red[g2][tid];
        float v = lrelu(t);
        float m = v;
        #pragma unroll
        for (int off = 8; off >= 1; off >>= 1)
            m = fmaxf(m, __shfl_xor(m, off, 64));
        float e = __expf(v - m);
        float ssum = e;
        #pragma unroll
        for (int off = 8; off >= 1; off >>= 1)
            ssum += __shfl_xor(ssum, off, 64);
        out[tid] = e / ssum;
    }
}

extern "C" void kernel_launch(void* const* d_in, const int* in_sizes, int n_in,
                              void* d_out, int out_size, void* d_ws, size_t ws_size,
                              hipStream_t stream) {
    const float* x        = (const float*)d_in[0];
    const float* edge_w   = (const float*)d_in[1];
    const float* out_w    = (const float*)d_in[2];
    const int*   edge_src = (const int*)d_in[3];
    const int*   edge_dst = (const int*)d_in[4];
    const int*   out_src  = (const int*)d_in[5];
    const int*   out_dst  = (const int*)d_in[6];

    float* partials = (float*)d_ws;                     // NBLK*NN floats (8 MB)
    float* accv     = partials + (size_t)NBLK * NN;     // NN floats
    float* outs     = accv + NN;                        // 256*NOUTC floats
    float* sink     = outs + 256 * NOUTC;               // DCE guard
    float* out      = (float*)d_out;

    for (int l = 0; l < NL; ++l) {
        const float* sv = (l == 0) ? x : accv;
        scatter_kernel<<<NBLK, NTHR, 0, stream>>>(
            sv,
            edge_src + (size_t)l * NE,
            edge_dst + (size_t)l * NE,
            edge_w   + (size_t)l * NE,
            partials);
        if (l + 1 < NL) {
            reduce_kernel<<<NBLK, 256, 0, stream>>>(
                partials, accv,
                edge_src + (size_t)(l + 1) * NE,
                edge_dst + (size_t)(l + 1) * NE,
                edge_w   + (size_t)(l + 1) * NE,
                EPB, sink);
        } else {
            reduce_kernel<<<NBLK, 256, 0, stream>>>(
                partials, accv,
                out_src, out_dst, out_w,
                EOUTC / NBLK, sink);
        }
    }

    out_scatter_kernel<<<256, 512, 0, stream>>>(accv, out_src, out_dst, out_w, outs);
    final_kernel<<<1, 256, 0, stream>>>(outs, out);
}